// Round 2
// baseline (1631.760 us; speedup 1.0000x reference)
//
#include <hip/hip_runtime.h>
#include <hip/hip_bf16.h>

// EntityTable: B=16,T=2048,D=1024,N_E=8,D_E=64
// Phase A (parallel): hp = h@Wi^T + bi ; logits = h@ek^T/32 ; w = softmax(logits)
//                     P  = W_ih @ hp   (entity-independent input-gate projection)
// Phase B (sequential scan over T): per cell (b,n):
//   gx_k = w*P_k + b_ih_k ; gh_k = W_hh[k]·s + b_hh_k
//   r=sig(gx0+gh0) z=sig(gx1+gh1) n=tanh(gx2 + r*gh2) ; s' = (1-z)n + z s
//
// Round-2: scan uses ONE raw s_barrier per step (lgkmcnt-only wait) so the
// per-step global prefetch loads and output stores never drain at barriers.
// Proj reads the Wi weights through a pre-transposed WT4 buffer (coalesced).

constexpr int B_  = 16;
constexpr int T_  = 2048;
constexpr int D_  = 1024;
constexpr int NE  = 8;
constexpr int DE  = 64;
constexpr int G3  = 192;            // 3*DE
constexpr int ROWS = B_ * T_;       // 32768
constexpr int OUT1OFF = ROWS * NE * DE;  // 16777216

// ---------------- Kernel T: transpose Wi -> WT4 ----------------
// WT4[(dq*64 + o)*4 + i] = Wi[o*1024 + dq*4 + i]   (dq in [0,256), o in [0,64))
__global__ __launch_bounds__(256) void wt_kernel(
    const float* __restrict__ Wi, float* __restrict__ WT4)
{
    const int o  = blockIdx.x;     // 64 blocks
    const int dq = threadIdx.x;    // 256 threads
    const float4 v = *(const float4*)&Wi[o * D_ + dq * 4];
    *(float4*)&WT4[(dq * 64 + o) * 4] = v;
}

// ---------------- Kernel A: projection + routing + P ----------------
constexpr int RPB = 32;   // rows per block
constexpr int CH  = 128;  // K-chunk

__global__ __launch_bounds__(256) void proj_kernel(
    const float* __restrict__ h,   const float* __restrict__ ek,
    const float* __restrict__ WT4, const float* __restrict__ bi,
    const float* __restrict__ Wih,
    float* __restrict__ Pout, float* __restrict__ wout)
{
    __shared__ float hch[RPB][CH];   // 16 KB
    __shared__ float hp[RPB][DE];    // 8 KB
    __shared__ float lg[RPB][NE];    // 1 KB

    const int tid = threadIdx.x;
    const int brow = blockIdx.x * RPB;
    const int w = tid >> 6;          // wave 0..3
    const int o = tid & 63;          // lane = output index for hp
    const int n  = o & 7;            // entity for logit partial
    const int sl = o >> 3;           // K-slice for logit partial

    float acc[8], accl[8];
#pragma unroll
    for (int r = 0; r < 8; ++r) { acc[r] = 0.f; accl[r] = 0.f; }

    for (int kc = 0; kc < D_; kc += CH) {
        __syncthreads();
        // cooperative load of h chunk: 32 rows x 128 (coalesced float4)
#pragma unroll
        for (int i = 0; i < 4; ++i) {
            int idx = tid + i * 256;
            int lr = idx >> 5;
            int c4 = (idx & 31) * 4;
            *(float4*)&hch[lr][c4] =
                *(const float4*)&h[(size_t)(brow + lr) * D_ + kc + c4];
        }
        __syncthreads();

        // hp accumulation: lane o owns output o; weights via coalesced WT4
        for (int d4 = 0; d4 < CH / 4; ++d4) {
            const float4 wt = *(const float4*)&WT4[((kc >> 2) + d4) * 256 + (o << 2)];
#pragma unroll
            for (int r = 0; r < 8; ++r) {
                const float4 h4 = *(const float4*)&hch[w * 8 + r][d4 * 4];
                acc[r] = fmaf(wt.x, h4.x,
                         fmaf(wt.y, h4.y,
                         fmaf(wt.z, h4.z,
                         fmaf(wt.w, h4.w, acc[r]))));
            }
        }
        // logits partial: lane handles entity n, K-slice sl (16 d's of this chunk)
#pragma unroll
        for (int i4 = 0; i4 < 4; ++i4) {
            const int dl = sl * 16 + i4 * 4;
            const float4 e4 = *(const float4*)&ek[n * D_ + kc + dl];
#pragma unroll
            for (int r = 0; r < 8; ++r) {
                const float4 h4 = *(const float4*)&hch[w * 8 + r][dl];
                accl[r] = fmaf(e4.x, h4.x,
                          fmaf(e4.y, h4.y,
                          fmaf(e4.z, h4.z,
                          fmaf(e4.w, h4.w, accl[r]))));
            }
        }
    }

    // finish hp -> LDS
    const float biv = bi[o];
#pragma unroll
    for (int r = 0; r < 8; ++r) hp[w * 8 + r][o] = acc[r] + biv;

    // reduce logit partials across the 8 K-slices (lanes with same o&7)
#pragma unroll
    for (int r = 0; r < 8; ++r) {
        accl[r] += __shfl_xor(accl[r], 8);
        accl[r] += __shfl_xor(accl[r], 16);
        accl[r] += __shfl_xor(accl[r], 32);
    }
    if (sl == 0) {
#pragma unroll
        for (int r = 0; r < 8; ++r) lg[w * 8 + r][n] = accl[r] * 0.03125f;
    }
    __syncthreads();

    // softmax over 8 entities (one thread per row)
    if (tid < RPB) {
        const int lr = tid;
        float v[NE];
        float m = -1e30f;
#pragma unroll
        for (int e = 0; e < NE; ++e) { v[e] = lg[lr][e]; m = fmaxf(m, v[e]); }
        float s = 0.f;
#pragma unroll
        for (int e = 0; e < NE; ++e) { v[e] = __expf(v[e] - m); s += v[e]; }
        const float inv = 1.f / s;
#pragma unroll
        for (int e = 0; e < NE; ++e)
            wout[(size_t)(brow + lr) * NE + e] = v[e] * inv;
    }

    // P = W_ih @ hp  (threads 0..191, k = thread)
    if (tid < G3) {
        const int k = tid;
        for (int lr0 = 0; lr0 < RPB; lr0 += 8) {
            float pacc[8];
#pragma unroll
            for (int r = 0; r < 8; ++r) pacc[r] = 0.f;
            for (int d4 = 0; d4 < DE / 4; ++d4) {
                const float4 wv = *(const float4*)&Wih[k * DE + d4 * 4];
#pragma unroll
                for (int r = 0; r < 8; ++r) {
                    const float4 h4 = *(const float4*)&hp[lr0 + r][d4 * 4];
                    pacc[r] = fmaf(wv.x, h4.x,
                              fmaf(wv.y, h4.y,
                              fmaf(wv.z, h4.z,
                              fmaf(wv.w, h4.w, pacc[r]))));
                }
            }
#pragma unroll
            for (int r = 0; r < 8; ++r)
                Pout[(size_t)(brow + lr0 + r) * G3 + k] = pacc[r];
        }
    }
}

// ---------------- Kernel B: sequential GRU scan, 1 raw barrier/step ----------------
// 128 blocks (one per (b,n) cell), 192 threads: wave w = gate w, lane j.
// Each wave keeps its own LDS copy of the state (no cross-wave dep for the dot)
// and redundantly computes the activation update.
__global__ __launch_bounds__(192) void scan_kernel(
    const float* __restrict__ P,   const float* __restrict__ route,
    const float* __restrict__ Whh, const float* __restrict__ bih,
    const float* __restrict__ bhh, const float* __restrict__ e0,
    float* __restrict__ out, int write1)
{
    __shared__ float s_l[3][DE];        // per-wave state copy
    __shared__ float g_l[2][4][DE];     // dbuf gate results: [buf][{a_r,a_z,u,v}][j]

    const int cell = blockIdx.x;
    const int b = cell >> 3;
    const int n = cell & 7;
    const int tid = threadIdx.x;        // 0..191
    const int wid = tid >> 6;           // 0..2 (gate)
    const int j   = tid & 63;           // lane
    const int k   = tid;                // gate-row index

    // W_hh row k in registers (64 floats)
    float wreg[DE];
#pragma unroll
    for (int i4 = 0; i4 < 16; ++i4)
        *(float4*)&wreg[i4 * 4] = *(const float4*)&Whh[k * DE + i4 * 4];
    const float bihk = bih[k];
    const float bhhk = bhh[k];
    const size_t row0 = (size_t)b * T_;

    float s_reg = e0[n * DE + j];
    s_l[wid][j] = s_reg;                // own-wave write; own-wave reads below

    const float* Prow = P + row0 * G3 + k;        // + t*G3 per step
    const float* wrow = route + row0 * NE + n;    // + t*NE per step

    float pc[4], wc[4], pn[4], wn[4];
#pragma unroll
    for (int i = 0; i < 4; ++i) {
        pc[i] = Prow[(size_t)i * G3];
        wc[i] = wrow[i * NE];
    }

    int buf = 0;

    for (int t0 = 0; t0 < T_; t0 += 4) {
        const int t4 = (t0 + 4 < T_) ? t0 + 4 : t0;   // last group reloads (harmless)
        // issue next group's prefetch — stays in flight across barriers (raw s_barrier)
#pragma unroll
        for (int i = 0; i < 4; ++i) {
            pn[i] = Prow[(size_t)(t4 + i) * G3];
            wn[i] = wrow[(t4 + i) * NE];
        }

#pragma unroll
        for (int i = 0; i < 4; ++i) {
            const int t = t0 + i;
            const float gx = fmaf(wc[i], pc[i], bihk);

            // gh = W_hh[k] . s  (LDS broadcast reads from own wave's copy)
            float a0 = 0.f, a1 = 0.f, a2 = 0.f, a3 = 0.f;
#pragma unroll
            for (int q = 0; q < 16; q += 4) {
                const float4 s0 = *(const float4*)&s_l[wid][(q + 0) * 4];
                const float4 s1 = *(const float4*)&s_l[wid][(q + 1) * 4];
                const float4 s2 = *(const float4*)&s_l[wid][(q + 2) * 4];
                const float4 s3 = *(const float4*)&s_l[wid][(q + 3) * 4];
                a0 = fmaf(wreg[(q+0)*4+0], s0.x, fmaf(wreg[(q+0)*4+1], s0.y,
                     fmaf(wreg[(q+0)*4+2], s0.z, fmaf(wreg[(q+0)*4+3], s0.w, a0))));
                a1 = fmaf(wreg[(q+1)*4+0], s1.x, fmaf(wreg[(q+1)*4+1], s1.y,
                     fmaf(wreg[(q+1)*4+2], s1.z, fmaf(wreg[(q+1)*4+3], s1.w, a1))));
                a2 = fmaf(wreg[(q+2)*4+0], s2.x, fmaf(wreg[(q+2)*4+1], s2.y,
                     fmaf(wreg[(q+2)*4+2], s2.z, fmaf(wreg[(q+2)*4+3], s2.w, a2))));
                a3 = fmaf(wreg[(q+3)*4+0], s3.x, fmaf(wreg[(q+3)*4+1], s3.y,
                     fmaf(wreg[(q+3)*4+2], s3.z, fmaf(wreg[(q+3)*4+3], s3.w, a3))));
            }
            const float gh = ((a0 + a1) + (a2 + a3)) + bhhk;

            if (wid == 0) {
                g_l[buf][0][j] = gx + gh;
            } else if (wid == 1) {
                g_l[buf][1][j] = gx + gh;
            } else {
                g_l[buf][2][j] = gx;
                g_l[buf][3][j] = gh;
            }

            // one barrier per step: LDS-only drain, vmcnt untouched
            asm volatile("s_waitcnt lgkmcnt(0)" ::: "memory");
            __builtin_amdgcn_s_barrier();

            const float ra = g_l[buf][0][j];
            const float za = g_l[buf][1][j];
            const float u  = g_l[buf][2][j];
            const float v  = g_l[buf][3][j];

            const float rr = 1.f / (1.f + __expf(-ra));
            const float zz = 1.f / (1.f + __expf(-za));
            const float x  = fmaf(rr, v, u);
            const float nn = 1.f - 2.f / (__expf(2.f * x) + 1.f);   // tanh(x)
            const float snew = fmaf(zz, s_reg - nn, nn);
            s_reg = snew;
            s_l[wid][j] = snew;          // own-wave write for next dot

            const size_t o0 = (row0 + t) * (size_t)(NE * DE) + n * DE + j;
            if (wid == 0) out[o0] = snew;
            if (write1 && wid == 1) out[OUT1OFF + o0] = snew;

            buf ^= 1;
        }

#pragma unroll
        for (int i = 0; i < 4; ++i) { pc[i] = pn[i]; wc[i] = wn[i]; }
    }
}

extern "C" void kernel_launch(void* const* d_in, const int* in_sizes, int n_in,
                              void* d_out, int out_size, void* d_ws, size_t ws_size,
                              hipStream_t stream) {
    const float* h_seq = (const float*)d_in[0];
    const float* ek    = (const float*)d_in[1];
    const float* Wi    = (const float*)d_in[2];
    const float* bi    = (const float*)d_in[3];
    const float* Wih   = (const float*)d_in[4];
    const float* Whh   = (const float*)d_in[5];
    const float* bih   = (const float*)d_in[6];
    const float* bhh   = (const float*)d_in[7];
    const float* e0    = (const float*)d_in[8];
    float* out = (float*)d_out;

    const size_t need = (size_t)ROWS * (G3 + NE) * sizeof(float)
                      + (size_t)DE * D_ * sizeof(float);  // ~26.5 MB
    float* wbuf;
    float* Pbuf;
    float* WT4;
    int write1;
    if (ws_size >= need) {
        wbuf = (float*)d_ws;
        Pbuf = wbuf + (size_t)ROWS * NE;
        WT4  = Pbuf + (size_t)ROWS * G3;
        write1 = 1;
    } else {
        // stash P/route/WT4 in the out1 region; replicate out0->out1 at the end
        wbuf = out + OUT1OFF;
        Pbuf = wbuf + (size_t)ROWS * NE;
        WT4  = Pbuf + (size_t)ROWS * G3;
        write1 = 0;
    }

    wt_kernel<<<DE, 256, 0, stream>>>(Wi, WT4);
    proj_kernel<<<ROWS / RPB, 256, 0, stream>>>(h_seq, ek, WT4, bi, Wih, Pbuf, wbuf);
    scan_kernel<<<B_ * NE, 192, 0, stream>>>(Pbuf, wbuf, Whh, bih, bhh, e0, out, write1);

    if (!write1) {
        hipMemcpyAsync(out + OUT1OFF, out, (size_t)OUT1OFF * sizeof(float),
                       hipMemcpyDeviceToDevice, stream);
    }
}